// Round 1
// baseline (723.409 us; speedup 1.0000x reference)
//
#include <hip/hip_runtime.h>

typedef _Float16 half8 __attribute__((ext_vector_type(8)));
typedef float floatx4 __attribute__((ext_vector_type(4)));

#define MFMA_F16(a, b, c) __builtin_amdgcn_mfma_f32_16x16x32_f16((a), (b), (c), 0, 0, 0)

__device__ __forceinline__ unsigned short f2h_bits(float f) {
    union { _Float16 h; unsigned short u; } cv;
    cv.h = (_Float16)f;
    return cv.u;
}

// ---------------------------------------------------------------- converts
__global__ void conv_x_kernel(const float* __restrict__ x, unsigned short* __restrict__ xb) {
    int i = blockIdx.x * 256 + threadIdx.x;          // one float4 per thread, exact grid
    float4 v = ((const float4*)x)[i];
    ushort4 o;
    o.x = f2h_bits(v.x); o.y = f2h_bits(v.y); o.z = f2h_bits(v.z); o.w = f2h_bits(v.w);
    ((ushort4*)xb)[i] = o;
}

// W_kqv [12][768][192] -> Wt [2304][768] f16, Q-columns (c in [64,128)) scaled by 0.125*log2(e)
__global__ void conv_wkqv_kernel(const float* __restrict__ w, unsigned short* __restrict__ wT) {
    int t = blockIdx.x * 256 + threadIdx.x;          // exact grid: 12*192*768
    int d = t % 768;
    int hc = t / 768;
    int h = hc / 192;
    int c = hc - h * 192;
    float v = w[(h * 768 + d) * 192 + c];
    if (c >= 64 && c < 128) v *= 0.18033688011112042f;   // (1/8) * log2(e)
    wT[t] = f2h_bits(v);
}

__global__ void conv_wproj_kernel(const float* __restrict__ w, unsigned short* __restrict__ wb) {
    int i = blockIdx.x * 256 + threadIdx.x;          // exact grid: 768*768/4
    float4 v = ((const float4*)w)[i];
    ushort4 o;
    o.x = f2h_bits(v.x); o.y = f2h_bits(v.y); o.z = f2h_bits(v.z); o.w = f2h_bits(v.w);
    ((ushort4*)wb)[i] = o;
}

// ---------------------------------------------------------------- GEMM  C = A[M,768] * Bt[N,768]^T
// 128x128 tile, BK=64, 4 waves (2x2), each wave 64x64 (4x4 x 16x16x32 MFMA).
// LDS staged via global_load_lds(16B); XOR swizzle (slot ^ row&7) applied on the GLOBAL
// source so LDS stays linear; ds_read_b128 applies the same XOR -> 2-way (free) banks.
// EPI==0: scatter K/Q/V (V transposed) f16.  EPI==1: fp32 out + bias.
template <int EPI>
__global__ __launch_bounds__(256, 2) void gemm_bt_kernel(
    const unsigned short* __restrict__ A, const unsigned short* __restrict__ Bt,
    unsigned short* __restrict__ o_q, unsigned short* __restrict__ o_k,
    unsigned short* __restrict__ o_vt, float* __restrict__ o_f32,
    const float* __restrict__ bias, int Ntiles) {
    __shared__ unsigned short sA[128 * 64];
    __shared__ unsigned short sB[128 * 64];
    const int tid = threadIdx.x;
    const int lo = tid & 15;
    const int hi = (tid >> 4) & 3;
    const int wid = tid >> 6;
    const int wr = wid >> 1;
    const int wc = wid & 1;
    const int bm = blockIdx.x / Ntiles;
    const int bn = blockIdx.x % Ntiles;
    const size_t rowA0 = (size_t)bm * 128;
    const size_t rowB0 = (size_t)bn * 128;

    const floatx4 ZERO = {0.f, 0.f, 0.f, 0.f};
    floatx4 acc[4][4];
#pragma unroll
    for (int i = 0; i < 4; ++i)
#pragma unroll
        for (int j = 0; j < 4; ++j) acc[i][j] = ZERO;

    const int ldsWaveBase = (tid & 0xC0) << 3;  // wid*512 ushorts (wave-uniform)

    for (int kt = 0; kt < 768; kt += 64) {
        __syncthreads();
#pragma unroll
        for (int it = 0; it < 4; ++it) {
            int g = it * 256 + tid;
            int row = g >> 3;
            int slot = g & 7;
            int koff = kt + ((slot ^ (row & 7)) << 3);  // pre-swizzled global source
            const unsigned short* srcA = A + (rowA0 + row) * 768 + koff;
            const unsigned short* srcB = Bt + (rowB0 + row) * 768 + koff;
            unsigned short* dA = &sA[it * 2048 + ldsWaveBase];
            unsigned short* dB = &sB[it * 2048 + ldsWaveBase];
            __builtin_amdgcn_global_load_lds(
                (const __attribute__((address_space(1))) unsigned int*)srcA,
                (__attribute__((address_space(3))) unsigned int*)dA, 16, 0, 0);
            __builtin_amdgcn_global_load_lds(
                (const __attribute__((address_space(1))) unsigned int*)srcB,
                (__attribute__((address_space(3))) unsigned int*)dB, 16, 0, 0);
        }
        __syncthreads();
#pragma unroll
        for (int kc = 0; kc < 2; ++kc) {
            half8 av[4], bv[4];
#pragma unroll
            for (int mi = 0; mi < 4; ++mi) {
                int row = wr * 64 + mi * 16 + lo;
                av[mi] = *(const half8*)&sA[row * 64 + (((kc * 4 + hi) ^ (lo & 7)) << 3)];
            }
#pragma unroll
            for (int ni = 0; ni < 4; ++ni) {
                int row = wc * 64 + ni * 16 + lo;
                bv[ni] = *(const half8*)&sB[row * 64 + (((kc * 4 + hi) ^ (lo & 7)) << 3)];
            }
#pragma unroll
            for (int mi = 0; mi < 4; ++mi)
#pragma unroll
                for (int ni = 0; ni < 4; ++ni)
                    acc[mi][ni] = MFMA_F16(av[mi], bv[ni], acc[mi][ni]);
        }
    }

    if (EPI == 0) {
#pragma unroll
        for (int ni = 0; ni < 4; ++ni) {
            int gn = (int)rowB0 + wc * 64 + ni * 16 + lo;   // [0,2304)
            unsigned h = (unsigned)gn / 192u;
            int c = gn - (int)h * 192;
#pragma unroll
            for (int mi = 0; mi < 4; ++mi) {
#pragma unroll
                for (int r = 0; r < 4; ++r) {
                    int gm = (int)rowA0 + wr * 64 + mi * 16 + hi * 4 + r;
                    int b = gm >> 12;
                    int n = gm & 4095;
                    int bh = b * 12 + (int)h;
                    unsigned short val = f2h_bits(acc[mi][ni][r]);
                    if (c < 64)
                        o_k[((size_t)bh * 4096 + n) * 64 + c] = val;
                    else if (c < 128)
                        o_q[((size_t)bh * 4096 + n) * 64 + (c - 64)] = val;
                    else
                        o_vt[((size_t)bh * 64 + (c - 128)) * 4096 + n] = val;
                }
            }
        }
    } else {
#pragma unroll
        for (int mi = 0; mi < 4; ++mi)
#pragma unroll
            for (int ni = 0; ni < 4; ++ni) {
                int gn = (int)rowB0 + wc * 64 + ni * 16 + lo;
                float bs = bias[gn];
#pragma unroll
                for (int r = 0; r < 4; ++r) {
                    int gm = (int)rowA0 + wr * 64 + mi * 16 + hi * 4 + r;
                    o_f32[(size_t)gm * 768 + gn] = acc[mi][ni][r] + bs;
                }
            }
    }
}

// ---------------------------------------------------------------- flash attention (causal)
// grid = 24 heads * 64 q-tiles; 4 waves/block, wave owns 16 q rows. KBLK=64.
// Scores already in log2 domain (scale folded into Q), online softmax via exp2f.
// P goes through wave-private XOR-swizzled LDS to reach the MFMA A-fragment layout.
__global__ __launch_bounds__(256) void attn_kernel(
    const unsigned short* __restrict__ Qw, const unsigned short* __restrict__ Kw,
    const unsigned short* __restrict__ Vtw, unsigned short* __restrict__ Ow) {
    __shared__ unsigned short sP[4][16 * 64];
    const int tid = threadIdx.x;
    const int lane = tid & 63;
    const int wid = tid >> 6;
    const int lo = lane & 15;
    const int hi = lane >> 4;
    const int bh = blockIdx.x >> 6;
    const int qt = (blockIdx.x & 63) << 6;
    const int qr0 = qt + wid * 16;

    const unsigned short* Qb = Qw + (size_t)bh * 4096 * 64;
    const unsigned short* Kb = Kw + (size_t)bh * 4096 * 64;
    const unsigned short* Vb = Vtw + (size_t)bh * 4096 * 64;

    const floatx4 ZERO = {0.f, 0.f, 0.f, 0.f};
    half8 aQ0 = *(const half8*)&Qb[(size_t)(qr0 + lo) * 64 + hi * 8];
    half8 aQ1 = *(const half8*)&Qb[(size_t)(qr0 + lo) * 64 + 32 + hi * 8];

    floatx4 accO[4];
    float mI[4], lI[4];
#pragma unroll
    for (int r = 0; r < 4; ++r) { accO[r] = ZERO; mI[r] = -1e30f; lI[r] = 0.f; }

    unsigned short* sp = sP[wid];
    const int kend = qr0 + 15;
    for (int kt = 0; kt <= kend; kt += 64) {
        floatx4 s[4];
#pragma unroll
        for (int c = 0; c < 4; ++c) {
            const unsigned short* kp = &Kb[(size_t)(kt + c * 16 + lo) * 64 + hi * 8];
            half8 b0 = *(const half8*)kp;
            half8 b1 = *(const half8*)(kp + 32);
            s[c] = MFMA_F16(aQ0, b0, ZERO);
            s[c] = MFMA_F16(aQ1, b1, s[c]);
        }
        if (kt + 63 > qr0) {  // diagonal tile: causal mask key > qrow
#pragma unroll
            for (int c = 0; c < 4; ++c) {
                int key = kt + c * 16 + lo;
#pragma unroll
                for (int r = 0; r < 4; ++r)
                    if (key > qr0 + hi * 4 + r) s[c][r] = -1e30f;
            }
        }
        float mx[4], rs[4];
#pragma unroll
        for (int r = 0; r < 4; ++r)
            mx[r] = fmaxf(fmaxf(s[0][r], s[1][r]), fmaxf(s[2][r], s[3][r]));
#pragma unroll
        for (int off = 1; off < 16; off <<= 1)
#pragma unroll
            for (int r = 0; r < 4; ++r)
                mx[r] = fmaxf(mx[r], __shfl_xor(mx[r], off, 64));

        float p[4][4];
#pragma unroll
        for (int r = 0; r < 4; ++r) {
            float mn = fmaxf(mI[r], mx[r]);
            float sc = exp2f(mI[r] - mn);
            mI[r] = mn;
            lI[r] *= sc;
#pragma unroll
            for (int db = 0; db < 4; ++db) accO[db][r] *= sc;
            float sum = 0.f;
#pragma unroll
            for (int c = 0; c < 4; ++c) {
                p[c][r] = exp2f(s[c][r] - mn);
                sum += p[c][r];
            }
            rs[r] = sum;
        }
#pragma unroll
        for (int off = 1; off < 16; off <<= 1)
#pragma unroll
            for (int r = 0; r < 4; ++r) rs[r] += __shfl_xor(rs[r], off, 64);
#pragma unroll
        for (int r = 0; r < 4; ++r) lI[r] += rs[r];

        // P[16 q][64 k] -> wave-private LDS, swizzled: slot ^= (row&7)
#pragma unroll
        for (int c = 0; c < 4; ++c) {
            int col = c * 16 + lo;
            int slot = col >> 3;
            int within = col & 7;
#pragma unroll
            for (int r = 0; r < 4; ++r) {
                int row = hi * 4 + r;
                sp[(row << 6) + ((slot ^ (row & 7)) << 3) + within] = f2h_bits(p[c][r]);
            }
        }
        half8 aP0 = *(const half8*)&sp[(lo << 6) + ((hi ^ (lo & 7)) << 3)];
        half8 aP1 = *(const half8*)&sp[(lo << 6) + (((4 + hi) ^ (lo & 7)) << 3)];
#pragma unroll
        for (int db = 0; db < 4; ++db) {
            const unsigned short* vp = &Vb[(size_t)(db * 16 + lo) * 4096 + kt + hi * 8];
            accO[db] = MFMA_F16(aP0, *(const half8*)vp, accO[db]);
            accO[db] = MFMA_F16(aP1, *(const half8*)(vp + 32), accO[db]);
        }
    }

    const int b = bh / 12;
    const int h = bh - b * 12;
#pragma unroll
    for (int r = 0; r < 4; ++r) {
        float inv = 1.0f / lI[r];
        int row = qr0 + hi * 4 + r;
        size_t base = ((size_t)(b * 4096 + row)) * 768 + h * 64 + lo;
#pragma unroll
        for (int db = 0; db < 4; ++db)
            Ow[base + db * 16] = f2h_bits(accO[db][r] * inv);
    }
}

// ---------------------------------------------------------------- launch
extern "C" void kernel_launch(void* const* d_in, const int* in_sizes, int n_in,
                              void* d_out, int out_size, void* d_ws, size_t ws_size,
                              hipStream_t stream) {
    const float* x = (const float*)d_in[0];
    const float* wkqv = (const float*)d_in[1];
    const float* wproj = (const float*)d_in[2];
    const float* bproj = (const float*)d_in[3];
    float* out = (float*)d_out;

    char* ws = (char*)d_ws;
    // layout (bytes): xb 12582912 | wkqvT 3538944 | wprojB 1179648 | Q 12582912 | K 12582912 | Vt 12582912
    unsigned short* xb = (unsigned short*)(ws);
    unsigned short* wkqvT = (unsigned short*)(ws + 12582912);
    unsigned short* wprojB = (unsigned short*)(ws + 16121856);
    unsigned short* Qw = (unsigned short*)(ws + 17301504);
    unsigned short* Kw = (unsigned short*)(ws + 29884416);
    unsigned short* Vtw = (unsigned short*)(ws + 42467328);
    unsigned short* Ow = xb;  // xb dead after KQV GEMM; reuse for attention output
    if (ws_size < 55050240) return;

    conv_x_kernel<<<6144, 256, 0, stream>>>(x, xb);
    conv_wkqv_kernel<<<6912, 256, 0, stream>>>(wkqv, wkqvT);
    conv_wproj_kernel<<<576, 256, 0, stream>>>(wproj, wprojB);
    gemm_bt_kernel<0><<<64 * 18, 256, 0, stream>>>(xb, wkqvT, Qw, Kw, Vtw, nullptr, nullptr, 18);
    attn_kernel<<<24 * 64, 256, 0, stream>>>(Qw, Kw, Vtw, Ow);
    gemm_bt_kernel<1><<<64 * 6, 256, 0, stream>>>(Ow, wprojB, nullptr, nullptr, nullptr, out, bproj, 6);
}

// Round 2
// 431.341 us; speedup vs baseline: 1.6771x; 1.6771x over previous
//
#include <hip/hip_runtime.h>

typedef _Float16 half8 __attribute__((ext_vector_type(8)));
typedef float floatx4 __attribute__((ext_vector_type(4)));

#define MFMA_F16(a, b, c) __builtin_amdgcn_mfma_f32_16x16x32_f16((a), (b), (c), 0, 0, 0)

__device__ __forceinline__ unsigned short f2h_bits(float f) {
    union { _Float16 h; unsigned short u; } cv;
    cv.h = (_Float16)f;
    return cv.u;
}

// ---------------------------------------------------------------- converts
__global__ void conv_x_kernel(const float* __restrict__ x, unsigned short* __restrict__ xb) {
    int i = blockIdx.x * 256 + threadIdx.x;          // one float4 per thread, exact grid
    float4 v = ((const float4*)x)[i];
    ushort4 o;
    o.x = f2h_bits(v.x); o.y = f2h_bits(v.y); o.z = f2h_bits(v.z); o.w = f2h_bits(v.w);
    ((ushort4*)xb)[i] = o;
}

// W_kqv [12][768][192] -> Wt [2304][768] f16, Q-columns (c in [64,128)) scaled by 0.125*log2(e)
__global__ void conv_wkqv_kernel(const float* __restrict__ w, unsigned short* __restrict__ wT) {
    int t = blockIdx.x * 256 + threadIdx.x;          // exact grid: 12*192*768
    int d = t % 768;
    int hc = t / 768;
    int h = hc / 192;
    int c = hc - h * 192;
    float v = w[(h * 768 + d) * 192 + c];
    if (c >= 64 && c < 128) v *= 0.18033688011112042f;   // (1/8) * log2(e)
    wT[t] = f2h_bits(v);
}

__global__ void conv_wproj_kernel(const float* __restrict__ w, unsigned short* __restrict__ wb) {
    int i = blockIdx.x * 256 + threadIdx.x;          // exact grid: 768*768/4
    float4 v = ((const float4*)w)[i];
    ushort4 o;
    o.x = f2h_bits(v.x); o.y = f2h_bits(v.y); o.z = f2h_bits(v.z); o.w = f2h_bits(v.w);
    ((ushort4*)wb)[i] = o;
}

// ---------------------------------------------------------------- GEMM  C = A[M,768] * Bt[N,768]^T
// 128x128 tile, BK=64, 4 waves (2x2), each wave 64x64 (4x4 x 16x16x32 MFMA).
// LDS staged via global_load_lds(16B); XOR swizzle (slot ^ row&7) applied on the GLOBAL
// source so LDS stays linear; ds_read_b128 applies the same XOR -> 2-way (free) banks.
// EPI==0: scatter K/Q/V (V transposed) f16.  EPI==1: fp32 out + bias.
template <int EPI>
__global__ __launch_bounds__(256, 2) void gemm_bt_kernel(
    const unsigned short* __restrict__ A, const unsigned short* __restrict__ Bt,
    unsigned short* __restrict__ o_q, unsigned short* __restrict__ o_k,
    unsigned short* __restrict__ o_vt, float* __restrict__ o_f32,
    const float* __restrict__ bias, int Ntiles) {
    __shared__ unsigned short sA[128 * 64];
    __shared__ unsigned short sB[128 * 64];
    const int tid = threadIdx.x;
    const int lo = tid & 15;
    const int hi = (tid >> 4) & 3;
    const int wid = tid >> 6;
    const int wr = wid >> 1;
    const int wc = wid & 1;
    const int bm = blockIdx.x / Ntiles;
    const int bn = blockIdx.x % Ntiles;
    const size_t rowA0 = (size_t)bm * 128;
    const size_t rowB0 = (size_t)bn * 128;

    const floatx4 ZERO = {0.f, 0.f, 0.f, 0.f};
    floatx4 acc[4][4];
#pragma unroll
    for (int i = 0; i < 4; ++i)
#pragma unroll
        for (int j = 0; j < 4; ++j) acc[i][j] = ZERO;

    const int ldsWaveBase = (tid & 0xC0) << 3;  // wid*512 ushorts (wave-uniform)

    for (int kt = 0; kt < 768; kt += 64) {
        __syncthreads();
#pragma unroll
        for (int it = 0; it < 4; ++it) {
            int g = it * 256 + tid;
            int row = g >> 3;
            int slot = g & 7;
            int koff = kt + ((slot ^ (row & 7)) << 3);  // pre-swizzled global source
            const unsigned short* srcA = A + (rowA0 + row) * 768 + koff;
            const unsigned short* srcB = Bt + (rowB0 + row) * 768 + koff;
            unsigned short* dA = &sA[it * 2048 + ldsWaveBase];
            unsigned short* dB = &sB[it * 2048 + ldsWaveBase];
            __builtin_amdgcn_global_load_lds(
                (const __attribute__((address_space(1))) unsigned int*)srcA,
                (__attribute__((address_space(3))) unsigned int*)dA, 16, 0, 0);
            __builtin_amdgcn_global_load_lds(
                (const __attribute__((address_space(1))) unsigned int*)srcB,
                (__attribute__((address_space(3))) unsigned int*)dB, 16, 0, 0);
        }
        __syncthreads();
#pragma unroll
        for (int kc = 0; kc < 2; ++kc) {
            half8 av[4], bv[4];
#pragma unroll
            for (int mi = 0; mi < 4; ++mi) {
                int row = wr * 64 + mi * 16 + lo;
                av[mi] = *(const half8*)&sA[row * 64 + (((kc * 4 + hi) ^ (lo & 7)) << 3)];
            }
#pragma unroll
            for (int ni = 0; ni < 4; ++ni) {
                int row = wc * 64 + ni * 16 + lo;
                bv[ni] = *(const half8*)&sB[row * 64 + (((kc * 4 + hi) ^ (lo & 7)) << 3)];
            }
#pragma unroll
            for (int mi = 0; mi < 4; ++mi)
#pragma unroll
                for (int ni = 0; ni < 4; ++ni)
                    acc[mi][ni] = MFMA_F16(av[mi], bv[ni], acc[mi][ni]);
        }
    }

    if (EPI == 0) {
#pragma unroll
        for (int ni = 0; ni < 4; ++ni) {
            int gn = (int)rowB0 + wc * 64 + ni * 16 + lo;   // [0,2304)
            unsigned h = (unsigned)gn / 192u;
            int c = gn - (int)h * 192;
#pragma unroll
            for (int mi = 0; mi < 4; ++mi) {
#pragma unroll
                for (int r = 0; r < 4; ++r) {
                    int gm = (int)rowA0 + wr * 64 + mi * 16 + hi * 4 + r;
                    int b = gm >> 12;
                    int n = gm & 4095;
                    int bh = b * 12 + (int)h;
                    unsigned short val = f2h_bits(acc[mi][ni][r]);
                    if (c < 64)
                        o_k[((size_t)bh * 4096 + n) * 64 + c] = val;
                    else if (c < 128)
                        o_q[((size_t)bh * 4096 + n) * 64 + (c - 64)] = val;
                    else
                        o_vt[((size_t)bh * 64 + (c - 128)) * 4096 + n] = val;
                }
            }
        }
    } else {
#pragma unroll
        for (int mi = 0; mi < 4; ++mi)
#pragma unroll
            for (int ni = 0; ni < 4; ++ni) {
                int gn = (int)rowB0 + wc * 64 + ni * 16 + lo;
                float bs = bias[gn];
#pragma unroll
                for (int r = 0; r < 4; ++r) {
                    int gm = (int)rowA0 + wr * 64 + mi * 16 + hi * 4 + r;
                    o_f32[(size_t)gm * 768 + gn] = acc[mi][ni][r] + bs;
                }
            }
    }
}

// ---------------------------------------------------------------- flash attention (causal)
// Block = 128 q-rows (4 waves x 32 rows), KBLK=64. Grid 24*32=768, qt-major DESCENDING
// (fixes the stride-256 ≡ 0 mod 64 dispatch imbalance of round 0: heavy tiles first,
// co-resident blocks now span the whole qt range).
// Per wave: 2 m-fragments of 16 rows; K tile register-prefetched one iteration ahead;
// V tile loaded before softmax so its latency hides under the exp2/shuffle chain.
// Scores in log2 domain (scale folded into Q). P staged via wave-private swizzled LDS.
__global__ __launch_bounds__(256, 2) void attn_kernel(
    const unsigned short* __restrict__ Qw, const unsigned short* __restrict__ Kw,
    const unsigned short* __restrict__ Vtw, unsigned short* __restrict__ Ow) {
    __shared__ unsigned short sP[4][32 * 64];
    const int tid = threadIdx.x;
    const int lane = tid & 63;
    const int wid = tid >> 6;
    const int lo = lane & 15;
    const int hi = lane >> 4;
    const int bh = blockIdx.x % 24;
    const int qtile = 31 - blockIdx.x / 24;
    const int qr0 = qtile * 128 + wid * 32;

    const unsigned short* Qb = Qw + (size_t)bh * 4096 * 64;
    const unsigned short* Kb = Kw + (size_t)bh * 4096 * 64;
    const unsigned short* Vb = Vtw + (size_t)bh * 4096 * 64;

    const floatx4 ZERO = {0.f, 0.f, 0.f, 0.f};
    half8 aQ[2][2];
#pragma unroll
    for (int m = 0; m < 2; ++m) {
        const unsigned short* qp = &Qb[(size_t)(qr0 + m * 16 + lo) * 64 + hi * 8];
        aQ[m][0] = *(const half8*)qp;
        aQ[m][1] = *(const half8*)(qp + 32);
    }

    floatx4 accO[2][4];
    float mI[2][4], lI[2][4];
#pragma unroll
    for (int m = 0; m < 2; ++m)
#pragma unroll
        for (int r = 0; r < 4; ++r) { accO[m][r] = ZERO; mI[m][r] = -1e30f; lI[m][r] = 0.f; }

    unsigned short* sp = sP[wid];
    const int kend = qr0 + 31;

    half8 Kc[4][2];
#pragma unroll
    for (int c = 0; c < 4; ++c) {
        const unsigned short* kp = &Kb[(size_t)(c * 16 + lo) * 64 + hi * 8];
        Kc[c][0] = *(const half8*)kp;
        Kc[c][1] = *(const half8*)(kp + 32);
    }

    for (int kt = 0; kt <= kend; kt += 64) {
        const bool more = (kt + 64 <= kend);
        half8 Kn[4][2];
        if (more) {  // prefetch next K tile (consumed next iteration)
#pragma unroll
            for (int c = 0; c < 4; ++c) {
                const unsigned short* kp = &Kb[(size_t)(kt + 64 + c * 16 + lo) * 64 + hi * 8];
                Kn[c][0] = *(const half8*)kp;
                Kn[c][1] = *(const half8*)(kp + 32);
            }
        }
        half8 Vv[4][2];  // V for THIS tile: issued now, used after softmax
#pragma unroll
        for (int db = 0; db < 4; ++db) {
            const unsigned short* vp = &Vb[(size_t)(db * 16 + lo) * 4096 + kt + hi * 8];
            Vv[db][0] = *(const half8*)vp;
            Vv[db][1] = *(const half8*)(vp + 32);
        }

        floatx4 s[2][4];
#pragma unroll
        for (int m = 0; m < 2; ++m)
#pragma unroll
            for (int c = 0; c < 4; ++c) {
                s[m][c] = MFMA_F16(aQ[m][0], Kc[c][0], ZERO);
                s[m][c] = MFMA_F16(aQ[m][1], Kc[c][1], s[m][c]);
            }
#pragma unroll
        for (int m = 0; m < 2; ++m) {
            const int qm0 = qr0 + m * 16;
            if (kt + 63 > qm0) {  // diagonal tiles: causal mask key > qrow
#pragma unroll
                for (int c = 0; c < 4; ++c) {
                    int key = kt + c * 16 + lo;
#pragma unroll
                    for (int r = 0; r < 4; ++r)
                        if (key > qm0 + hi * 4 + r) s[m][c][r] = -1e30f;
                }
            }
        }

        float mx[2][4];
#pragma unroll
        for (int m = 0; m < 2; ++m)
#pragma unroll
            for (int r = 0; r < 4; ++r)
                mx[m][r] = fmaxf(fmaxf(s[m][0][r], s[m][1][r]), fmaxf(s[m][2][r], s[m][3][r]));
#pragma unroll
        for (int off = 1; off < 16; off <<= 1)
#pragma unroll
            for (int m = 0; m < 2; ++m)
#pragma unroll
                for (int r = 0; r < 4; ++r)
                    mx[m][r] = fmaxf(mx[m][r], __shfl_xor(mx[m][r], off, 64));

        float rs[2][4];
#pragma unroll
        for (int m = 0; m < 2; ++m)
#pragma unroll
            for (int r = 0; r < 4; ++r) {
                float mn = fmaxf(mI[m][r], mx[m][r]);
                float sc = exp2f(mI[m][r] - mn);
                mI[m][r] = mn;
                lI[m][r] *= sc;
#pragma unroll
                for (int db = 0; db < 4; ++db) accO[m][db][r] *= sc;
                const int row = m * 16 + hi * 4 + r;
                const int rowbase = row << 6;
                const int rx = row & 7;
                float sum = 0.f;
#pragma unroll
                for (int c = 0; c < 4; ++c) {
                    float p = exp2f(s[m][c][r] - mn);
                    sum += p;
                    int col = c * 16 + lo;
                    sp[rowbase + (((col >> 3) ^ rx) << 3) + (col & 7)] = f2h_bits(p);
                }
                rs[m][r] = sum;
            }
#pragma unroll
        for (int off = 1; off < 16; off <<= 1)
#pragma unroll
            for (int m = 0; m < 2; ++m)
#pragma unroll
                for (int r = 0; r < 4; ++r)
                    rs[m][r] += __shfl_xor(rs[m][r], off, 64);
#pragma unroll
        for (int m = 0; m < 2; ++m)
#pragma unroll
            for (int r = 0; r < 4; ++r) lI[m][r] += rs[m][r];

#pragma unroll
        for (int m = 0; m < 2; ++m) {
            const int rbase = (m * 16 + lo) << 6;
            half8 aP0 = *(const half8*)&sp[rbase + ((hi ^ (lo & 7)) << 3)];
            half8 aP1 = *(const half8*)&sp[rbase + (((4 + hi) ^ (lo & 7)) << 3)];
#pragma unroll
            for (int db = 0; db < 4; ++db) {
                accO[m][db] = MFMA_F16(aP0, Vv[db][0], accO[m][db]);
                accO[m][db] = MFMA_F16(aP1, Vv[db][1], accO[m][db]);
            }
        }

        if (more) {
#pragma unroll
            for (int c = 0; c < 4; ++c) { Kc[c][0] = Kn[c][0]; Kc[c][1] = Kn[c][1]; }
        }
    }

    const int b = bh / 12;
    const int h = bh - b * 12;
#pragma unroll
    for (int m = 0; m < 2; ++m)
#pragma unroll
        for (int r = 0; r < 4; ++r) {
            float inv = 1.0f / lI[m][r];
            int row = qr0 + m * 16 + hi * 4 + r;
            size_t base = ((size_t)(b * 4096 + row)) * 768 + h * 64 + lo;
#pragma unroll
            for (int db = 0; db < 4; ++db)
                Ow[base + db * 16] = f2h_bits(accO[m][db][r] * inv);
        }
}

// ---------------------------------------------------------------- launch
extern "C" void kernel_launch(void* const* d_in, const int* in_sizes, int n_in,
                              void* d_out, int out_size, void* d_ws, size_t ws_size,
                              hipStream_t stream) {
    const float* x = (const float*)d_in[0];
    const float* wkqv = (const float*)d_in[1];
    const float* wproj = (const float*)d_in[2];
    const float* bproj = (const float*)d_in[3];
    float* out = (float*)d_out;

    char* ws = (char*)d_ws;
    // layout (bytes): xb 12582912 | wkqvT 3538944 | wprojB 1179648 | Q 12582912 | K 12582912 | Vt 12582912
    unsigned short* xb = (unsigned short*)(ws);
    unsigned short* wkqvT = (unsigned short*)(ws + 12582912);
    unsigned short* wprojB = (unsigned short*)(ws + 16121856);
    unsigned short* Qw = (unsigned short*)(ws + 17301504);
    unsigned short* Kw = (unsigned short*)(ws + 29884416);
    unsigned short* Vtw = (unsigned short*)(ws + 42467328);
    unsigned short* Ow = xb;  // xb dead after KQV GEMM; reuse for attention output
    if (ws_size < 55050240) return;

    conv_x_kernel<<<6144, 256, 0, stream>>>(x, xb);
    conv_wkqv_kernel<<<6912, 256, 0, stream>>>(wkqv, wkqvT);
    conv_wproj_kernel<<<576, 256, 0, stream>>>(wproj, wprojB);
    gemm_bt_kernel<0><<<64 * 18, 256, 0, stream>>>(xb, wkqvT, Qw, Kw, Vtw, nullptr, nullptr, 18);
    attn_kernel<<<768, 256, 0, stream>>>(Qw, Kw, Vtw, Ow);
    gemm_bt_kernel<1><<<64 * 6, 256, 0, stream>>>(Ow, wprojB, nullptr, nullptr, nullptr, out, bproj, 6);
}

// Round 4
// 313.605 us; speedup vs baseline: 2.3068x; 1.3754x over previous
//
#include <hip/hip_runtime.h>

typedef _Float16 half8 __attribute__((ext_vector_type(8)));
typedef __fp16 fp16x2 __attribute__((ext_vector_type(2)));
typedef float floatx4 __attribute__((ext_vector_type(4)));
typedef float floatx16 __attribute__((ext_vector_type(16)));

#define MFMA_F16(a, b, c) __builtin_amdgcn_mfma_f32_16x16x32_f16((a), (b), (c), 0, 0, 0)
#define MFMA32(a, b, c) __builtin_amdgcn_mfma_f32_32x32x16_f16((a), (b), (c), 0, 0, 0)

__device__ __forceinline__ unsigned short f2h_bits(float f) {
    union { _Float16 h; unsigned short u; } cv;
    cv.h = (_Float16)f;
    return cv.u;
}

__device__ __forceinline__ unsigned pkrtz(float a, float b) {
    union { fp16x2 h; unsigned u; } cv;
    cv.h = __builtin_amdgcn_cvt_pkrtz(a, b);
    return cv.u;
}

// permlane32_swap(a,b): r0 = {a.lo32, b.lo32}, r1 = {a.hi32, b.hi32} (lane-half swap)
__device__ __forceinline__ void swap32(unsigned a, unsigned b, int hi32,
                                       unsigned& r0, unsigned& r1) {
#if __has_builtin(__builtin_amdgcn_permlane32_swap)
    auto r = __builtin_amdgcn_permlane32_swap((int)a, (int)b, false, false);
    r0 = (unsigned)r[0];
    r1 = (unsigned)r[1];
#else
    unsigned ax = (unsigned)__shfl_xor((int)a, 32, 64);
    unsigned bx = (unsigned)__shfl_xor((int)b, 32, 64);
    r0 = hi32 ? bx : a;
    r1 = hi32 ? b : ax;
#endif
}

// ---------------------------------------------------------------- converts
__global__ void conv_x_kernel(const float* __restrict__ x, unsigned short* __restrict__ xb) {
    int i = blockIdx.x * 256 + threadIdx.x;          // one float4 per thread, exact grid
    float4 v = ((const float4*)x)[i];
    ushort4 o;
    o.x = f2h_bits(v.x); o.y = f2h_bits(v.y); o.z = f2h_bits(v.z); o.w = f2h_bits(v.w);
    ((ushort4*)xb)[i] = o;
}

// W_kqv [12][768][192] -> Wt [2304][768] f16, Q-columns (c in [64,128)) scaled by 0.125*log2(e)
__global__ void conv_wkqv_kernel(const float* __restrict__ w, unsigned short* __restrict__ wT) {
    int t = blockIdx.x * 256 + threadIdx.x;          // exact grid: 12*192*768
    int d = t % 768;
    int hc = t / 768;
    int h = hc / 192;
    int c = hc - h * 192;
    float v = w[(h * 768 + d) * 192 + c];
    if (c >= 64 && c < 128) v *= 0.18033688011112042f;   // (1/8) * log2(e)
    wT[t] = f2h_bits(v);
}

__global__ void conv_wproj_kernel(const float* __restrict__ w, unsigned short* __restrict__ wb) {
    int i = blockIdx.x * 256 + threadIdx.x;          // exact grid: 768*768/4
    float4 v = ((const float4*)w)[i];
    ushort4 o;
    o.x = f2h_bits(v.x); o.y = f2h_bits(v.y); o.z = f2h_bits(v.z); o.w = f2h_bits(v.w);
    ((ushort4*)wb)[i] = o;
}

// ---------------------------------------------------------------- GEMM  C = A[M,768] * Bt[N,768]^T
// (unchanged from round 1 — verified)
template <int EPI>
__global__ __launch_bounds__(256, 2) void gemm_bt_kernel(
    const unsigned short* __restrict__ A, const unsigned short* __restrict__ Bt,
    unsigned short* __restrict__ o_q, unsigned short* __restrict__ o_k,
    unsigned short* __restrict__ o_vt, float* __restrict__ o_f32,
    const float* __restrict__ bias, int Ntiles) {
    __shared__ unsigned short sA[128 * 64];
    __shared__ unsigned short sB[128 * 64];
    const int tid = threadIdx.x;
    const int lo = tid & 15;
    const int hi = (tid >> 4) & 3;
    const int wid = tid >> 6;
    const int wr = wid >> 1;
    const int wc = wid & 1;
    const int bm = blockIdx.x / Ntiles;
    const int bn = blockIdx.x % Ntiles;
    const size_t rowA0 = (size_t)bm * 128;
    const size_t rowB0 = (size_t)bn * 128;

    const floatx4 ZERO = {0.f, 0.f, 0.f, 0.f};
    floatx4 acc[4][4];
#pragma unroll
    for (int i = 0; i < 4; ++i)
#pragma unroll
        for (int j = 0; j < 4; ++j) acc[i][j] = ZERO;

    const int ldsWaveBase = (tid & 0xC0) << 3;  // wid*512 ushorts (wave-uniform)

    for (int kt = 0; kt < 768; kt += 64) {
        __syncthreads();
#pragma unroll
        for (int it = 0; it < 4; ++it) {
            int g = it * 256 + tid;
            int row = g >> 3;
            int slot = g & 7;
            int koff = kt + ((slot ^ (row & 7)) << 3);  // pre-swizzled global source
            const unsigned short* srcA = A + (rowA0 + row) * 768 + koff;
            const unsigned short* srcB = Bt + (rowB0 + row) * 768 + koff;
            unsigned short* dA = &sA[it * 2048 + ldsWaveBase];
            unsigned short* dB = &sB[it * 2048 + ldsWaveBase];
            __builtin_amdgcn_global_load_lds(
                (const __attribute__((address_space(1))) unsigned int*)srcA,
                (__attribute__((address_space(3))) unsigned int*)dA, 16, 0, 0);
            __builtin_amdgcn_global_load_lds(
                (const __attribute__((address_space(1))) unsigned int*)srcB,
                (__attribute__((address_space(3))) unsigned int*)dB, 16, 0, 0);
        }
        __syncthreads();
#pragma unroll
        for (int kc = 0; kc < 2; ++kc) {
            half8 av[4], bv[4];
#pragma unroll
            for (int mi = 0; mi < 4; ++mi) {
                int row = wr * 64 + mi * 16 + lo;
                av[mi] = *(const half8*)&sA[row * 64 + (((kc * 4 + hi) ^ (lo & 7)) << 3)];
            }
#pragma unroll
            for (int ni = 0; ni < 4; ++ni) {
                int row = wc * 64 + ni * 16 + lo;
                bv[ni] = *(const half8*)&sB[row * 64 + (((kc * 4 + hi) ^ (lo & 7)) << 3)];
            }
#pragma unroll
            for (int mi = 0; mi < 4; ++mi)
#pragma unroll
                for (int ni = 0; ni < 4; ++ni)
                    acc[mi][ni] = MFMA_F16(av[mi], bv[ni], acc[mi][ni]);
        }
    }

    if (EPI == 0) {
#pragma unroll
        for (int ni = 0; ni < 4; ++ni) {
            int gn = (int)rowB0 + wc * 64 + ni * 16 + lo;   // [0,2304)
            unsigned h = (unsigned)gn / 192u;
            int c = gn - (int)h * 192;
#pragma unroll
            for (int mi = 0; mi < 4; ++mi) {
#pragma unroll
                for (int r = 0; r < 4; ++r) {
                    int gm = (int)rowA0 + wr * 64 + mi * 16 + hi * 4 + r;
                    int b = gm >> 12;
                    int n = gm & 4095;
                    int bh = b * 12 + (int)h;
                    unsigned short val = f2h_bits(acc[mi][ni][r]);
                    if (c < 64)
                        o_k[((size_t)bh * 4096 + n) * 64 + c] = val;
                    else if (c < 128)
                        o_q[((size_t)bh * 4096 + n) * 64 + (c - 64)] = val;
                    else
                        o_vt[((size_t)bh * 64 + (c - 128)) * 4096 + n] = val;
                }
            }
        }
    } else {
#pragma unroll
        for (int mi = 0; mi < 4; ++mi)
#pragma unroll
            for (int ni = 0; ni < 4; ++ni) {
                int gn = (int)rowB0 + wc * 64 + ni * 16 + lo;
                float bs = bias[gn];
#pragma unroll
                for (int r = 0; r < 4; ++r) {
                    int gm = (int)rowA0 + wr * 64 + mi * 16 + hi * 4 + r;
                    o_f32[(size_t)gm * 768 + gn] = acc[mi][ni][r] + bs;
                }
            }
    }
}

// ---------------------------------------------------------------- flash attention (causal)
// Swapped-QK^T 32x32 structure (T12): S^T = mfma_32x32x16(K, Q) puts a full q-row's
// k-values LANE-LOCAL (lane owns q = q0 + (lane&31); 16 of 32 tile-k's in regs, partner
// lane^32 owns the other 16). Softmax = in-register tree + ONE shfl_xor(32).
// P -> PV A-fragment built in-register: cvt_pkrtz pairs + permlane32_swap. No LDS at all.
// Defer-max (THR=8): accO rescale (cross-lane via 16x ds_bpermute) triggers rarely.
// V consumed via Vt[d][k] so PV B-fragments are contiguous 16B loads.
// crow(reg) = (reg&3) + 8*(reg>>2) + 4*hi32  (C/D row map, guide §3 m74/m101)
__global__ __launch_bounds__(256, 2) void attn_kernel(
    const unsigned short* __restrict__ Qw, const unsigned short* __restrict__ Kw,
    const unsigned short* __restrict__ Vtw, unsigned short* __restrict__ Ow) {
    const int tid = threadIdx.x;
    const int lane = tid & 63;
    const int wid = tid >> 6;
    const int l31 = lane & 31;
    const int hi32 = lane >> 5;
    const int bh = blockIdx.x % 24;
    const int qtile = 31 - blockIdx.x / 24;   // descending: heavy blocks first
    const int q0 = qtile * 128 + wid * 32;    // wave's 32-row q band
    const int myq = q0 + l31;

    const unsigned short* Qb = Qw + (size_t)bh * 4096 * 64;
    const unsigned short* Kb = Kw + (size_t)bh * 4096 * 64;
    const unsigned short* Vb = Vtw + (size_t)bh * 4096 * 64;

    // Q fragments (B-operand): lane holds q-row = myq, d = ds*16 + hi32*8 + j
    half8 qf[4];
#pragma unroll
    for (int ds = 0; ds < 4; ++ds)
        qf[ds] = *(const half8*)&Qb[(size_t)myq * 64 + ds * 16 + hi32 * 8];

    const floatx16 Z16 = {0.f,0.f,0.f,0.f,0.f,0.f,0.f,0.f,0.f,0.f,0.f,0.f,0.f,0.f,0.f,0.f};
    floatx16 accO0 = Z16, accO1 = Z16;  // O tiles [32q x 32d], d0 = 0 / 32
    float mI = -1e30f, lI = 0.f;

    const int ntiles = (q0 >> 5) + 1;   // k-tiles of 32, kt <= q0

    // K fragments (A-operand) for tile 0: lane holds k-row = kt + l31, d contiguous
    half8 kf[4];
#pragma unroll
    for (int ds = 0; ds < 4; ++ds)
        kf[ds] = *(const half8*)&Kb[(size_t)l31 * 64 + ds * 16 + hi32 * 8];

    for (int t = 0; t < ntiles; ++t) {
        const int kt = t << 5;
        // V fragments for THIS tile (issue early; used after softmax)
        half8 vf[2][2];
#pragma unroll
        for (int dt = 0; dt < 2; ++dt)
#pragma unroll
            for (int ks = 0; ks < 2; ++ks)
                vf[dt][ks] = *(const half8*)&Vb[(size_t)(dt * 32 + l31) * 4096 + kt + ks * 16 + hi32 * 8];
        // K prefetch for next tile
        const bool more = (t + 1 < ntiles);
        half8 kn[4];
        if (more) {
#pragma unroll
            for (int ds = 0; ds < 4; ++ds)
                kn[ds] = *(const half8*)&Kb[(size_t)(kt + 32 + l31) * 64 + ds * 16 + hi32 * 8];
        }

        // S^T[k][q] accumulate over d: lane owns q-col = l31, k-rows crow(reg)
        floatx16 s = Z16;
#pragma unroll
        for (int ds = 0; ds < 4; ++ds) s = MFMA32(kf[ds], qf[ds], s);

        if (kt + 31 > q0) {  // diagonal tile only: mask key > myq
#pragma unroll
            for (int r = 0; r < 16; ++r) {
                int key = kt + (r & 3) + ((r >> 2) << 3) + (hi32 << 2);
                if (key > myq) s[r] = -1e30f;
            }
        }

        // tile max: balanced in-register tree + partner half
        float m0 = fmaxf(s[0], s[1]),   m1 = fmaxf(s[2], s[3]);
        float m2 = fmaxf(s[4], s[5]),   m3 = fmaxf(s[6], s[7]);
        float m4 = fmaxf(s[8], s[9]),   m5 = fmaxf(s[10], s[11]);
        float m6 = fmaxf(s[12], s[13]), m7 = fmaxf(s[14], s[15]);
        float mx = fmaxf(fmaxf(fmaxf(m0, m1), fmaxf(m2, m3)),
                         fmaxf(fmaxf(m4, m5), fmaxf(m6, m7)));
        mx = fmaxf(mx, __shfl_xor(mx, 32, 64));

        // defer-max: rescale only when some row's max grew past THR=8 (log2 domain)
        if (!__all(mx <= mI + 8.0f)) {
            float mn = fmaxf(mI, mx);
            float sc = exp2f(mI - mn);
            mI = mn;
            lI *= sc;
#pragma unroll
            for (int r = 0; r < 16; ++r) {
                int src = (r & 3) + ((r >> 2) << 3) + (hi32 << 2);
                float scb = __int_as_float(
                    __builtin_amdgcn_ds_bpermute(src << 2, __float_as_int(sc)));
                accO0[r] *= scb;
                accO1[r] *= scb;
            }
        }

        // P = exp2(s - m); row sum (own 16 + partner)
        float e[16];
#pragma unroll
        for (int r = 0; r < 16; ++r) e[r] = exp2f(s[r] - mI);
        float a0 = (e[0] + e[1]) + (e[2] + e[3]);
        float a1 = (e[4] + e[5]) + (e[6] + e[7]);
        float a2 = (e[8] + e[9]) + (e[10] + e[11]);
        float a3 = (e[12] + e[13]) + (e[14] + e[15]);
        float ps = (a0 + a1) + (a2 + a3);
        lI += ps + __shfl_xor(ps, 32, 64);

        // pack P -> A fragments. Own regs hold k-pairs; partner holds complementary 8-run.
        unsigned pA0 = pkrtz(e[0], e[1]),   pA1 = pkrtz(e[2], e[3]);
        unsigned pB0 = pkrtz(e[4], e[5]),   pB1 = pkrtz(e[6], e[7]);
        unsigned pC0 = pkrtz(e[8], e[9]),   pC1 = pkrtz(e[10], e[11]);
        unsigned pD0 = pkrtz(e[12], e[13]), pD1 = pkrtz(e[14], e[15]);
        unsigned w0, w1, w2, w3, u0, u1, u2, u3;
        swap32(pA0, pB0, hi32, w0, w2);
        swap32(pA1, pB1, hi32, w1, w3);
        swap32(pC0, pD0, hi32, u0, u2);
        swap32(pC1, pD1, hi32, u1, u3);
        union { unsigned u[4]; half8 h; } f0, f1;
        f0.u[0] = w0; f0.u[1] = w1; f0.u[2] = w2; f0.u[3] = w3;  // k = ks0: 0..15
        f1.u[0] = u0; f1.u[1] = u1; f1.u[2] = u2; f1.u[3] = u3;  // k = ks1: 16..31

        // PV: accO[dt] += P[:, ks] x V[ks, dt]
        accO0 = MFMA32(f0.h, vf[0][0], accO0);
        accO0 = MFMA32(f1.h, vf[0][1], accO0);
        accO1 = MFMA32(f0.h, vf[1][0], accO1);
        accO1 = MFMA32(f1.h, vf[1][1], accO1);

        if (more) {
#pragma unroll
            for (int ds = 0; ds < 4; ++ds) kf[ds] = kn[ds];
        }
    }

    // epilogue: O[q][d] = accO / l[q]; broadcast 1/l to C-layout rows
    const float linv = 1.0f / lI;
    const int b = bh / 12;
    const int h = bh - b * 12;
#pragma unroll
    for (int r = 0; r < 16; ++r) {
        int crow = (r & 3) + ((r >> 2) << 3) + (hi32 << 2);
        float lb = __int_as_float(
            __builtin_amdgcn_ds_bpermute(crow << 2, __float_as_int(linv)));
        int qrow = q0 + crow;
        size_t base = ((size_t)(b * 4096 + qrow)) * 768 + h * 64;
        Ow[base + l31] = f2h_bits(accO0[r] * lb);
        Ow[base + 32 + l31] = f2h_bits(accO1[r] * lb);
    }
}

// ---------------------------------------------------------------- launch
extern "C" void kernel_launch(void* const* d_in, const int* in_sizes, int n_in,
                              void* d_out, int out_size, void* d_ws, size_t ws_size,
                              hipStream_t stream) {
    const float* x = (const float*)d_in[0];
    const float* wkqv = (const float*)d_in[1];
    const float* wproj = (const float*)d_in[2];
    const float* bproj = (const float*)d_in[3];
    float* out = (float*)d_out;

    char* ws = (char*)d_ws;
    // layout (bytes): xb 12582912 | wkqvT 3538944 | wprojB 1179648 | Q 12582912 | K 12582912 | Vt 12582912
    unsigned short* xb = (unsigned short*)(ws);
    unsigned short* wkqvT = (unsigned short*)(ws + 12582912);
    unsigned short* wprojB = (unsigned short*)(ws + 16121856);
    unsigned short* Qw = (unsigned short*)(ws + 17301504);
    unsigned short* Kw = (unsigned short*)(ws + 29884416);
    unsigned short* Vtw = (unsigned short*)(ws + 42467328);
    unsigned short* Ow = xb;  // xb dead after KQV GEMM; reuse for attention output
    if (ws_size < 55050240) return;

    conv_x_kernel<<<6144, 256, 0, stream>>>(x, xb);
    conv_wkqv_kernel<<<6912, 256, 0, stream>>>(wkqv, wkqvT);
    conv_wproj_kernel<<<576, 256, 0, stream>>>(wproj, wprojB);
    gemm_bt_kernel<0><<<64 * 18, 256, 0, stream>>>(xb, wkqvT, Qw, Kw, Vtw, nullptr, nullptr, 18);
    attn_kernel<<<768, 256, 0, stream>>>(Qw, Kw, Vtw, Ow);
    gemm_bt_kernel<1><<<64 * 6, 256, 0, stream>>>(Ow, wprojB, nullptr, nullptr, nullptr, out, bproj, 6);
}

// Round 5
// 205.929 us; speedup vs baseline: 3.5129x; 1.5229x over previous
//
#include <hip/hip_runtime.h>

typedef _Float16 half8 __attribute__((ext_vector_type(8)));
typedef __fp16 fp16x2 __attribute__((ext_vector_type(2)));
typedef float floatx4 __attribute__((ext_vector_type(4)));
typedef float floatx16 __attribute__((ext_vector_type(16)));

#define MFMA_F16(a, b, c) __builtin_amdgcn_mfma_f32_16x16x32_f16((a), (b), (c), 0, 0, 0)
#define MFMA32(a, b, c) __builtin_amdgcn_mfma_f32_32x32x16_f16((a), (b), (c), 0, 0, 0)

__device__ __forceinline__ unsigned short f2h_bits(float f) {
    union { _Float16 h; unsigned short u; } cv;
    cv.h = (_Float16)f;
    return cv.u;
}

__device__ __forceinline__ unsigned pkrtz(float a, float b) {
    union { fp16x2 h; unsigned u; } cv;
    cv.h = __builtin_amdgcn_cvt_pkrtz(a, b);
    return cv.u;
}

// permlane32_swap(a,b): r0 = {a.lo32, b.lo32}, r1 = {a.hi32, b.hi32} (lane-half swap)
__device__ __forceinline__ void swap32(unsigned a, unsigned b, int hi32,
                                       unsigned& r0, unsigned& r1) {
#if __has_builtin(__builtin_amdgcn_permlane32_swap)
    auto r = __builtin_amdgcn_permlane32_swap((int)a, (int)b, false, false);
    r0 = (unsigned)r[0];
    r1 = (unsigned)r[1];
#else
    unsigned ax = (unsigned)__shfl_xor((int)a, 32, 64);
    unsigned bx = (unsigned)__shfl_xor((int)b, 32, 64);
    r0 = hi32 ? bx : a;
    r1 = hi32 ? b : ax;
#endif
}

// ---------------------------------------------------------------- converts
__global__ void conv_x_kernel(const float* __restrict__ x, unsigned short* __restrict__ xb) {
    int i = blockIdx.x * 256 + threadIdx.x;          // one float4 per thread, exact grid
    float4 v = ((const float4*)x)[i];
    ushort4 o;
    o.x = f2h_bits(v.x); o.y = f2h_bits(v.y); o.z = f2h_bits(v.z); o.w = f2h_bits(v.w);
    ((ushort4*)xb)[i] = o;
}

// W_kqv [12][768][192] -> Wt [2304][768] f16, Q-columns (c in [64,128)) scaled by 0.125*log2(e)
__global__ void conv_wkqv_kernel(const float* __restrict__ w, unsigned short* __restrict__ wT) {
    int t = blockIdx.x * 256 + threadIdx.x;          // exact grid: 12*192*768
    int d = t % 768;
    int hc = t / 768;
    int h = hc / 192;
    int c = hc - h * 192;
    float v = w[(h * 768 + d) * 192 + c];
    if (c >= 64 && c < 128) v *= 0.18033688011112042f;   // (1/8) * log2(e)
    wT[t] = f2h_bits(v);
}

__global__ void conv_wproj_kernel(const float* __restrict__ w, unsigned short* __restrict__ wb) {
    int i = blockIdx.x * 256 + threadIdx.x;          // exact grid: 768*768/4
    float4 v = ((const float4*)w)[i];
    ushort4 o;
    o.x = f2h_bits(v.x); o.y = f2h_bits(v.y); o.z = f2h_bits(v.z); o.w = f2h_bits(v.w);
    ((ushort4*)wb)[i] = o;
}

// ---------------------------------------------------------------- GEMM  C = A[M,768] * Bt[N,768]^T
// 128x128 tile, BK=64, 4 waves. EPI==0: scatter K/Q/V into FRAGMENT-MAJOR layouts
// (per 32-k-tile, per 16B-lane-chunk — so the attention kernel's loads are fully
// coalesced 16B/lane instead of 128B/8KB-stride gathers). EPI==1: fp32 out + bias.
template <int EPI>
__global__ __launch_bounds__(256, 2) void gemm_bt_kernel(
    const unsigned short* __restrict__ A, const unsigned short* __restrict__ Bt,
    unsigned short* __restrict__ o_q, unsigned short* __restrict__ o_k,
    unsigned short* __restrict__ o_vt, float* __restrict__ o_f32,
    const float* __restrict__ bias, int Ntiles) {
    __shared__ unsigned short sA[128 * 64];
    __shared__ unsigned short sB[128 * 64];
    const int tid = threadIdx.x;
    const int lo = tid & 15;
    const int hi = (tid >> 4) & 3;
    const int wid = tid >> 6;
    const int wr = wid >> 1;
    const int wc = wid & 1;
    const int bm = blockIdx.x / Ntiles;
    const int bn = blockIdx.x % Ntiles;
    const size_t rowA0 = (size_t)bm * 128;
    const size_t rowB0 = (size_t)bn * 128;

    const floatx4 ZERO = {0.f, 0.f, 0.f, 0.f};
    floatx4 acc[4][4];
#pragma unroll
    for (int i = 0; i < 4; ++i)
#pragma unroll
        for (int j = 0; j < 4; ++j) acc[i][j] = ZERO;

    const int ldsWaveBase = (tid & 0xC0) << 3;  // wid*512 ushorts (wave-uniform)

    for (int kt = 0; kt < 768; kt += 64) {
        __syncthreads();
#pragma unroll
        for (int it = 0; it < 4; ++it) {
            int g = it * 256 + tid;
            int row = g >> 3;
            int slot = g & 7;
            int koff = kt + ((slot ^ (row & 7)) << 3);  // pre-swizzled global source
            const unsigned short* srcA = A + (rowA0 + row) * 768 + koff;
            const unsigned short* srcB = Bt + (rowB0 + row) * 768 + koff;
            unsigned short* dA = &sA[it * 2048 + ldsWaveBase];
            unsigned short* dB = &sB[it * 2048 + ldsWaveBase];
            __builtin_amdgcn_global_load_lds(
                (const __attribute__((address_space(1))) unsigned int*)srcA,
                (__attribute__((address_space(3))) unsigned int*)dA, 16, 0, 0);
            __builtin_amdgcn_global_load_lds(
                (const __attribute__((address_space(1))) unsigned int*)srcB,
                (__attribute__((address_space(3))) unsigned int*)dB, 16, 0, 0);
        }
        __syncthreads();
#pragma unroll
        for (int kc = 0; kc < 2; ++kc) {
            half8 av[4], bv[4];
#pragma unroll
            for (int mi = 0; mi < 4; ++mi) {
                int row = wr * 64 + mi * 16 + lo;
                av[mi] = *(const half8*)&sA[row * 64 + (((kc * 4 + hi) ^ (lo & 7)) << 3)];
            }
#pragma unroll
            for (int ni = 0; ni < 4; ++ni) {
                int row = wc * 64 + ni * 16 + lo;
                bv[ni] = *(const half8*)&sB[row * 64 + (((kc * 4 + hi) ^ (lo & 7)) << 3)];
            }
#pragma unroll
            for (int mi = 0; mi < 4; ++mi)
#pragma unroll
                for (int ni = 0; ni < 4; ++ni)
                    acc[mi][ni] = MFMA_F16(av[mi], bv[ni], acc[mi][ni]);
        }
    }

    if (EPI == 0) {
#pragma unroll
        for (int ni = 0; ni < 4; ++ni) {
            int gn = (int)rowB0 + wc * 64 + ni * 16 + lo;   // [0,2304)
            unsigned h = (unsigned)gn / 192u;
            int c = gn - (int)h * 192;
#pragma unroll
            for (int mi = 0; mi < 4; ++mi) {
#pragma unroll
                for (int r = 0; r < 4; ++r) {
                    int gm = (int)rowA0 + wr * 64 + mi * 16 + hi * 4 + r;
                    int b = gm >> 12;
                    int n = gm & 4095;
                    int bh = b * 12 + (int)h;
                    unsigned short val = f2h_bits(acc[mi][ni][r]);
                    // fragment-major scatter: element -> (tile, frag-slice, lane, j)
                    if (c < 64) {          // K: k=n, d=c
                        int t = n >> 5;
                        size_t idx = ((((size_t)bh * 128 + t) * 4 + (c >> 4)) * 64 +
                                      (((c >> 3) & 1) * 32 + (n & 31))) * 8 + (c & 7);
                        o_k[idx] = val;
                    } else if (c < 128) {  // Q: q=n, d=c-64
                        int d = c - 64;
                        int t = n >> 5;
                        size_t idx = ((((size_t)bh * 128 + t) * 4 + (d >> 4)) * 64 +
                                      (((d >> 3) & 1) * 32 + (n & 31))) * 8 + (d & 7);
                        o_q[idx] = val;
                    } else {               // V: k=n, dv=c-128
                        int dv = c - 128;
                        int t = n >> 5;
                        int kin = n & 31;
                        size_t idx = ((((size_t)bh * 128 + t) * 4 +
                                       ((dv >> 5) * 2 + (kin >> 4))) * 64 +
                                      (((kin >> 3) & 1) * 32 + (dv & 31))) * 8 + (kin & 7);
                        o_vt[idx] = val;
                    }
                }
            }
        }
    } else {
#pragma unroll
        for (int mi = 0; mi < 4; ++mi)
#pragma unroll
            for (int ni = 0; ni < 4; ++ni) {
                int gn = (int)rowB0 + wc * 64 + ni * 16 + lo;
                float bs = bias[gn];
#pragma unroll
                for (int r = 0; r < 4; ++r) {
                    int gm = (int)rowA0 + wr * 64 + mi * 16 + hi * 4 + r;
                    o_f32[(size_t)gm * 768 + gn] = acc[mi][ni][r] + bs;
                }
            }
    }
}

// ---------------------------------------------------------------- flash attention (causal)
// Swapped-QK^T 32x32 structure; softmax fully in-register (see round-2 notes).
// K/Q/V now in FRAGMENT-MAJOR layout: each fragment load is 16B/lane, lane-contiguous
// (1KB coalesced per instruction, base + imm offsets) — removes the 128B/8KB-stride
// gathers that made round 4 TCP-issue-bound. 2-wave blocks (1536, descending bands)
// for finer load balance; bh = blk%24 gives each XCD a ~3-head L2 working set.
__global__ __launch_bounds__(128) void attn_kernel(
    const unsigned short* __restrict__ Qw, const unsigned short* __restrict__ Kw,
    const unsigned short* __restrict__ Vtw, unsigned short* __restrict__ Ow) {
    const int tid = threadIdx.x;
    const int lane = tid & 63;
    const int wid = tid >> 6;
    const int l31 = lane & 31;
    const int hi32 = lane >> 5;
    const int bh = blockIdx.x % 24;
    const int band = 63 - blockIdx.x / 24;    // descending: heavy blocks first
    const int q0 = band * 64 + wid * 32;      // wave's 32-row q band
    const int qt32 = q0 >> 5;
    const int myq = q0 + l31;

    const unsigned short* QF = Qw + (size_t)bh * 262144;
    const unsigned short* KF = Kw + (size_t)bh * 262144;
    const unsigned short* VF = Vtw + (size_t)bh * 262144;

    // Q fragments (B-operand): q-row = myq, d = ds*16 + hi32*8 + j
    half8 qf[4];
#pragma unroll
    for (int ds = 0; ds < 4; ++ds)
        qf[ds] = *(const half8*)&QF[(((size_t)qt32 * 4 + ds) * 64 + lane) * 8];

    const floatx16 Z16 = {0.f,0.f,0.f,0.f,0.f,0.f,0.f,0.f,0.f,0.f,0.f,0.f,0.f,0.f,0.f,0.f};
    floatx16 accO0 = Z16, accO1 = Z16;  // O tiles [32q x 32d], d0 = 0 / 32
    float mI = -1e30f, lI = 0.f;

    const int ntiles = qt32 + 1;   // k-tiles of 32, kt <= q0

    half8 kf[4];
#pragma unroll
    for (int ds = 0; ds < 4; ++ds)
        kf[ds] = *(const half8*)&KF[((size_t)ds * 64 + lane) * 8];

    for (int t = 0; t < ntiles; ++t) {
        const int kt = t << 5;
        // V fragments for THIS tile (issue early; used after softmax)
        const unsigned short* vbase = &VF[(size_t)t * 2048 + lane * 8];
        half8 vf[2][2];
#pragma unroll
        for (int dt = 0; dt < 2; ++dt)
#pragma unroll
            for (int ks = 0; ks < 2; ++ks)
                vf[dt][ks] = *(const half8*)(vbase + (dt * 2 + ks) * 512);
        // K prefetch for next tile
        const bool more = (t + 1 < ntiles);
        half8 kn[4];
        if (more) {
            const unsigned short* kbase = &KF[(size_t)(t + 1) * 2048 + lane * 8];
#pragma unroll
            for (int ds = 0; ds < 4; ++ds)
                kn[ds] = *(const half8*)(kbase + ds * 512);
        }

        // S^T[k][q] accumulate over d: lane owns q-col = l31, k-rows crow(reg)
        floatx16 s = Z16;
        __builtin_amdgcn_s_setprio(1);
#pragma unroll
        for (int ds = 0; ds < 4; ++ds) s = MFMA32(kf[ds], qf[ds], s);
        __builtin_amdgcn_s_setprio(0);

        if (kt + 31 > q0) {  // diagonal tile only: mask key > myq
#pragma unroll
            for (int r = 0; r < 16; ++r) {
                int key = kt + (r & 3) + ((r >> 2) << 3) + (hi32 << 2);
                if (key > myq) s[r] = -1e30f;
            }
        }

        // tile max: balanced in-register tree + partner half
        float m0 = fmaxf(s[0], s[1]),   m1 = fmaxf(s[2], s[3]);
        float m2 = fmaxf(s[4], s[5]),   m3 = fmaxf(s[6], s[7]);
        float m4 = fmaxf(s[8], s[9]),   m5 = fmaxf(s[10], s[11]);
        float m6 = fmaxf(s[12], s[13]), m7 = fmaxf(s[14], s[15]);
        float mx = fmaxf(fmaxf(fmaxf(m0, m1), fmaxf(m2, m3)),
                         fmaxf(fmaxf(m4, m5), fmaxf(m6, m7)));
        mx = fmaxf(mx, __shfl_xor(mx, 32, 64));

        // defer-max: rescale only when some row's max grew past THR=8 (log2 domain)
        if (!__all(mx <= mI + 8.0f)) {
            float mn = fmaxf(mI, mx);
            float sc = exp2f(mI - mn);
            mI = mn;
            lI *= sc;
#pragma unroll
            for (int r = 0; r < 16; ++r) {
                int src = (r & 3) + ((r >> 2) << 3) + (hi32 << 2);
                float scb = __int_as_float(
                    __builtin_amdgcn_ds_bpermute(src << 2, __float_as_int(sc)));
                accO0[r] *= scb;
                accO1[r] *= scb;
            }
        }

        // P = exp2(s - m); row sum (own 16 + partner)
        float e[16];
#pragma unroll
        for (int r = 0; r < 16; ++r) e[r] = exp2f(s[r] - mI);
        float a0 = (e[0] + e[1]) + (e[2] + e[3]);
        float a1 = (e[4] + e[5]) + (e[6] + e[7]);
        float a2 = (e[8] + e[9]) + (e[10] + e[11]);
        float a3 = (e[12] + e[13]) + (e[14] + e[15]);
        float ps = (a0 + a1) + (a2 + a3);
        lI += ps + __shfl_xor(ps, 32, 64);

        // pack P -> A fragments. Own regs hold k-pairs; partner holds complementary 8-run.
        unsigned pA0 = pkrtz(e[0], e[1]),   pA1 = pkrtz(e[2], e[3]);
        unsigned pB0 = pkrtz(e[4], e[5]),   pB1 = pkrtz(e[6], e[7]);
        unsigned pC0 = pkrtz(e[8], e[9]),   pC1 = pkrtz(e[10], e[11]);
        unsigned pD0 = pkrtz(e[12], e[13]), pD1 = pkrtz(e[14], e[15]);
        unsigned w0, w1, w2, w3, u0, u1, u2, u3;
        swap32(pA0, pB0, hi32, w0, w2);
        swap32(pA1, pB1, hi32, w1, w3);
        swap32(pC0, pD0, hi32, u0, u2);
        swap32(pC1, pD1, hi32, u1, u3);
        union { unsigned u[4]; half8 h; } f0, f1;
        f0.u[0] = w0; f0.u[1] = w1; f0.u[2] = w2; f0.u[3] = w3;  // k = 0..15
        f1.u[0] = u0; f1.u[1] = u1; f1.u[2] = u2; f1.u[3] = u3;  // k = 16..31

        // PV: accO[dt] += P[:, ks] x V[ks, dt]
        __builtin_amdgcn_s_setprio(1);
        accO0 = MFMA32(f0.h, vf[0][0], accO0);
        accO0 = MFMA32(f1.h, vf[0][1], accO0);
        accO1 = MFMA32(f0.h, vf[1][0], accO1);
        accO1 = MFMA32(f1.h, vf[1][1], accO1);
        __builtin_amdgcn_s_setprio(0);

        if (more) {
#pragma unroll
            for (int ds = 0; ds < 4; ++ds) kf[ds] = kn[ds];
        }
    }

    // epilogue: O[q][d] = accO / l[q]; broadcast 1/l to C-layout rows
    const float linv = 1.0f / lI;
    const int b = bh / 12;
    const int h = bh - b * 12;
#pragma unroll
    for (int r = 0; r < 16; ++r) {
        int crow = (r & 3) + ((r >> 2) << 3) + (hi32 << 2);
        float lb = __int_as_float(
            __builtin_amdgcn_ds_bpermute(crow << 2, __float_as_int(linv)));
        int qrow = q0 + crow;
        size_t base = ((size_t)(b * 4096 + qrow)) * 768 + h * 64;
        Ow[base + l31] = f2h_bits(accO0[r] * lb);
        Ow[base + 32 + l31] = f2h_bits(accO1[r] * lb);
    }
}

// ---------------------------------------------------------------- launch
extern "C" void kernel_launch(void* const* d_in, const int* in_sizes, int n_in,
                              void* d_out, int out_size, void* d_ws, size_t ws_size,
                              hipStream_t stream) {
    const float* x = (const float*)d_in[0];
    const float* wkqv = (const float*)d_in[1];
    const float* wproj = (const float*)d_in[2];
    const float* bproj = (const float*)d_in[3];
    float* out = (float*)d_out;

    char* ws = (char*)d_ws;
    // layout (bytes): xb 12582912 | wkqvT 3538944 | wprojB 1179648 | Q 12582912 | K 12582912 | Vt 12582912
    unsigned short* xb = (unsigned short*)(ws);
    unsigned short* wkqvT = (unsigned short*)(ws + 12582912);
    unsigned short* wprojB = (unsigned short*)(ws + 16121856);
    unsigned short* Qw = (unsigned short*)(ws + 17301504);
    unsigned short* Kw = (unsigned short*)(ws + 29884416);
    unsigned short* Vtw = (unsigned short*)(ws + 42467328);
    unsigned short* Ow = xb;  // xb dead after KQV GEMM; reuse for attention output
    if (ws_size < 55050240) return;

    conv_x_kernel<<<6144, 256, 0, stream>>>(x, xb);
    conv_wkqv_kernel<<<6912, 256, 0, stream>>>(wkqv, wkqvT);
    conv_wproj_kernel<<<576, 256, 0, stream>>>(wproj, wprojB);
    gemm_bt_kernel<0><<<64 * 18, 256, 0, stream>>>(xb, wkqvT, Qw, Kw, Vtw, nullptr, nullptr, 18);
    attn_kernel<<<1536, 128, 0, stream>>>(Qw, Kw, Vtw, Ow);
    gemm_bt_kernel<1><<<64 * 6, 256, 0, stream>>>(Ow, wprojB, nullptr, nullptr, nullptr, out, bproj, 6);
}

// Round 6
// 203.442 us; speedup vs baseline: 3.5558x; 1.0122x over previous
//
#include <hip/hip_runtime.h>

typedef _Float16 half8 __attribute__((ext_vector_type(8)));
typedef __fp16 fp16x2 __attribute__((ext_vector_type(2)));
typedef float floatx4 __attribute__((ext_vector_type(4)));
typedef float floatx16 __attribute__((ext_vector_type(16)));

#define MFMA_F16(a, b, c) __builtin_amdgcn_mfma_f32_16x16x32_f16((a), (b), (c), 0, 0, 0)
#define MFMA32(a, b, c) __builtin_amdgcn_mfma_f32_32x32x16_f16((a), (b), (c), 0, 0, 0)

__device__ __forceinline__ unsigned short f2h_bits(float f) {
    union { _Float16 h; unsigned short u; } cv;
    cv.h = (_Float16)f;
    return cv.u;
}

__device__ __forceinline__ unsigned pkrtz(float a, float b) {
    union { fp16x2 h; unsigned u; } cv;
    cv.h = __builtin_amdgcn_cvt_pkrtz(a, b);
    return cv.u;
}

// permlane32_swap(a,b): r0 = {a.lo32, b.lo32}, r1 = {a.hi32, b.hi32} (lane-half swap)
__device__ __forceinline__ void swap32(unsigned a, unsigned b, int hi32,
                                       unsigned& r0, unsigned& r1) {
#if __has_builtin(__builtin_amdgcn_permlane32_swap)
    auto r = __builtin_amdgcn_permlane32_swap((int)a, (int)b, false, false);
    r0 = (unsigned)r[0];
    r1 = (unsigned)r[1];
#else
    unsigned ax = (unsigned)__shfl_xor((int)a, 32, 64);
    unsigned bx = (unsigned)__shfl_xor((int)b, 32, 64);
    r0 = hi32 ? bx : a;
    r1 = hi32 ? b : ax;
#endif
}

// cross-half max/add: fmax/add(own, partner) for every lane, pure VALU (no DS)
__device__ __forceinline__ float xhalf_max(float x) {
#if __has_builtin(__builtin_amdgcn_permlane32_swap)
    auto r = __builtin_amdgcn_permlane32_swap(__float_as_int(x), __float_as_int(x), false, false);
    return fmaxf(__int_as_float(r[0]), __int_as_float(r[1]));
#else
    return fmaxf(x, __shfl_xor(x, 32, 64));
#endif
}
__device__ __forceinline__ float xhalf_add(float x) {
#if __has_builtin(__builtin_amdgcn_permlane32_swap)
    auto r = __builtin_amdgcn_permlane32_swap(__float_as_int(x), __float_as_int(x), false, false);
    return __int_as_float(r[0]) + __int_as_float(r[1]);
#else
    return x + __shfl_xor(x, 32, 64);
#endif
}

// ---------------------------------------------------------------- converts
__global__ void conv_x_kernel(const float* __restrict__ x, unsigned short* __restrict__ xb) {
    int i = blockIdx.x * 256 + threadIdx.x;          // one float4 per thread, exact grid
    float4 v = ((const float4*)x)[i];
    ushort4 o;
    o.x = f2h_bits(v.x); o.y = f2h_bits(v.y); o.z = f2h_bits(v.z); o.w = f2h_bits(v.w);
    ((ushort4*)xb)[i] = o;
}

// W_kqv [12][768][192] -> Wt [2304][768] f16, Q-columns (c in [64,128)) scaled by 0.125*log2(e)
__global__ void conv_wkqv_kernel(const float* __restrict__ w, unsigned short* __restrict__ wT) {
    int t = blockIdx.x * 256 + threadIdx.x;          // exact grid: 12*192*768
    int d = t % 768;
    int hc = t / 768;
    int h = hc / 192;
    int c = hc - h * 192;
    float v = w[(h * 768 + d) * 192 + c];
    if (c >= 64 && c < 128) v *= 0.18033688011112042f;   // (1/8) * log2(e)
    wT[t] = f2h_bits(v);
}

__global__ void conv_wproj_kernel(const float* __restrict__ w, unsigned short* __restrict__ wb) {
    int i = blockIdx.x * 256 + threadIdx.x;          // exact grid: 768*768/4
    float4 v = ((const float4*)w)[i];
    ushort4 o;
    o.x = f2h_bits(v.x); o.y = f2h_bits(v.y); o.z = f2h_bits(v.z); o.w = f2h_bits(v.w);
    ((ushort4*)wb)[i] = o;
}

// ---------------------------------------------------------------- GEMM  C = A[M,768] * Bt[N,768]^T
// 128x128 tile, BK=64, 4 waves. EPI==0: scatter K/Q/V into FRAGMENT-MAJOR layouts.
// EPI==1: fp32 out + bias. (verified rounds 1-5)
template <int EPI>
__global__ __launch_bounds__(256, 2) void gemm_bt_kernel(
    const unsigned short* __restrict__ A, const unsigned short* __restrict__ Bt,
    unsigned short* __restrict__ o_q, unsigned short* __restrict__ o_k,
    unsigned short* __restrict__ o_vt, float* __restrict__ o_f32,
    const float* __restrict__ bias, int Ntiles) {
    __shared__ unsigned short sA[128 * 64];
    __shared__ unsigned short sB[128 * 64];
    const int tid = threadIdx.x;
    const int lo = tid & 15;
    const int hi = (tid >> 4) & 3;
    const int wid = tid >> 6;
    const int wr = wid >> 1;
    const int wc = wid & 1;
    const int bm = blockIdx.x / Ntiles;
    const int bn = blockIdx.x % Ntiles;
    const size_t rowA0 = (size_t)bm * 128;
    const size_t rowB0 = (size_t)bn * 128;

    const floatx4 ZERO = {0.f, 0.f, 0.f, 0.f};
    floatx4 acc[4][4];
#pragma unroll
    for (int i = 0; i < 4; ++i)
#pragma unroll
        for (int j = 0; j < 4; ++j) acc[i][j] = ZERO;

    const int ldsWaveBase = (tid & 0xC0) << 3;  // wid*512 ushorts (wave-uniform)

    for (int kt = 0; kt < 768; kt += 64) {
        __syncthreads();
#pragma unroll
        for (int it = 0; it < 4; ++it) {
            int g = it * 256 + tid;
            int row = g >> 3;
            int slot = g & 7;
            int koff = kt + ((slot ^ (row & 7)) << 3);  // pre-swizzled global source
            const unsigned short* srcA = A + (rowA0 + row) * 768 + koff;
            const unsigned short* srcB = Bt + (rowB0 + row) * 768 + koff;
            unsigned short* dA = &sA[it * 2048 + ldsWaveBase];
            unsigned short* dB = &sB[it * 2048 + ldsWaveBase];
            __builtin_amdgcn_global_load_lds(
                (const __attribute__((address_space(1))) unsigned int*)srcA,
                (__attribute__((address_space(3))) unsigned int*)dA, 16, 0, 0);
            __builtin_amdgcn_global_load_lds(
                (const __attribute__((address_space(1))) unsigned int*)srcB,
                (__attribute__((address_space(3))) unsigned int*)dB, 16, 0, 0);
        }
        __syncthreads();
#pragma unroll
        for (int kc = 0; kc < 2; ++kc) {
            half8 av[4], bv[4];
#pragma unroll
            for (int mi = 0; mi < 4; ++mi) {
                int row = wr * 64 + mi * 16 + lo;
                av[mi] = *(const half8*)&sA[row * 64 + (((kc * 4 + hi) ^ (lo & 7)) << 3)];
            }
#pragma unroll
            for (int ni = 0; ni < 4; ++ni) {
                int row = wc * 64 + ni * 16 + lo;
                bv[ni] = *(const half8*)&sB[row * 64 + (((kc * 4 + hi) ^ (lo & 7)) << 3)];
            }
#pragma unroll
            for (int mi = 0; mi < 4; ++mi)
#pragma unroll
                for (int ni = 0; ni < 4; ++ni)
                    acc[mi][ni] = MFMA_F16(av[mi], bv[ni], acc[mi][ni]);
        }
    }

    if (EPI == 0) {
#pragma unroll
        for (int ni = 0; ni < 4; ++ni) {
            int gn = (int)rowB0 + wc * 64 + ni * 16 + lo;   // [0,2304)
            unsigned h = (unsigned)gn / 192u;
            int c = gn - (int)h * 192;
#pragma unroll
            for (int mi = 0; mi < 4; ++mi) {
#pragma unroll
                for (int r = 0; r < 4; ++r) {
                    int gm = (int)rowA0 + wr * 64 + mi * 16 + hi * 4 + r;
                    int b = gm >> 12;
                    int n = gm & 4095;
                    int bh = b * 12 + (int)h;
                    unsigned short val = f2h_bits(acc[mi][ni][r]);
                    // fragment-major scatter: element -> (tile, frag-slice, lane, j)
                    if (c < 64) {          // K: k=n, d=c
                        int t = n >> 5;
                        size_t idx = ((((size_t)bh * 128 + t) * 4 + (c >> 4)) * 64 +
                                      (((c >> 3) & 1) * 32 + (n & 31))) * 8 + (c & 7);
                        o_k[idx] = val;
                    } else if (c < 128) {  // Q: q=n, d=c-64
                        int d = c - 64;
                        int t = n >> 5;
                        size_t idx = ((((size_t)bh * 128 + t) * 4 + (d >> 4)) * 64 +
                                      (((d >> 3) & 1) * 32 + (n & 31))) * 8 + (d & 7);
                        o_q[idx] = val;
                    } else {               // V: k=n, dv=c-128
                        int dv = c - 128;
                        int t = n >> 5;
                        int kin = n & 31;
                        size_t idx = ((((size_t)bh * 128 + t) * 4 +
                                       ((dv >> 5) * 2 + (kin >> 4))) * 64 +
                                      (((kin >> 3) & 1) * 32 + (dv & 31))) * 8 + (kin & 7);
                        o_vt[idx] = val;
                    }
                }
            }
        }
    } else {
#pragma unroll
        for (int mi = 0; mi < 4; ++mi)
#pragma unroll
            for (int ni = 0; ni < 4; ++ni) {
                int gn = (int)rowB0 + wc * 64 + ni * 16 + lo;
                float bs = bias[gn];
#pragma unroll
                for (int r = 0; r < 4; ++r) {
                    int gm = (int)rowA0 + wr * 64 + mi * 16 + hi * 4 + r;
                    o_f32[(size_t)gm * 768 + gn] = acc[mi][ni][r] + bs;
                }
            }
    }
}

// ---------------------------------------------------------------- flash attention (causal)
// Swapped-QK^T 32x32, fragment-major K/Q/V (rounds 2-5, verified).
// NEW: (a) causal band-pairing — wave handles bands {p, 127-p} sequentially, so EVERY
// wave does exactly 65 fat iterations (kills triangular drain tail); (b) KBLK=64 —
// two 32-k subtiles share one softmax pass (one max tree / exchange / sum / branch
// per 64 keys, 2x ILP in trees); (c) cross-half reductions via permlane32_swap
// (pure VALU) instead of shfl_xor DS ops; (d) mask provably only on last iteration.
// bh = blk%24 -> all 32 blocks of a head on one XCD (3 heads ~ 3MB fits L2).
__global__ __launch_bounds__(128, 2) void attn_kernel(
    const unsigned short* __restrict__ Qw, const unsigned short* __restrict__ Kw,
    const unsigned short* __restrict__ Vtw, unsigned short* __restrict__ Ow) {
    const int tid = threadIdx.x;
    const int lane = tid & 63;
    const int wid = tid >> 6;
    const int l31 = lane & 31;
    const int hi32 = lane >> 5;
    const int bh = blockIdx.x % 24;
    const int p = (blockIdx.x / 24) * 2 + wid;   // pair index 0..63
    const int b = bh / 12;
    const int h = bh - b * 12;

    const unsigned short* QF = Qw + (size_t)bh * 262144;
    const unsigned short* KF = Kw + (size_t)bh * 262144;
    const unsigned short* VF = Vtw + (size_t)bh * 262144;

    const floatx16 Z16 = {0.f,0.f,0.f,0.f,0.f,0.f,0.f,0.f,0.f,0.f,0.f,0.f,0.f,0.f,0.f,0.f};

    for (int pass = 0; pass < 2; ++pass) {
        const int band = pass ? 127 - p : p;     // 32-row band; covers all 128 exactly once
        const int q0 = band << 5;
        const int myq = q0 + l31;
        const int nk = (band >> 1) + 1;          // # of 64-key iterations (= ceil((band+1)/2))

        half8 qf[4];
#pragma unroll
        for (int ds = 0; ds < 4; ++ds)
            qf[ds] = *(const half8*)&QF[(((size_t)band * 4 + ds) * 64 + lane) * 8];

        floatx16 accO0 = Z16, accO1 = Z16;
        float mI = -1e30f, lI = 0.f;

        // K fragments for subtiles 0,1 of iteration 0 (fragment data exists for all k)
        half8 kfa[4], kfb[4];
#pragma unroll
        for (int ds = 0; ds < 4; ++ds) {
            kfa[ds] = *(const half8*)&KF[((size_t)ds * 64 + lane) * 8];
            kfb[ds] = *(const half8*)&KF[((size_t)(4 + ds) * 64 + lane) * 8];
        }

        for (int i = 0; i < nk; ++i) {
            const int kt = i << 6;
            // V for THIS iteration (both subtiles); issued early, used after softmax
            const unsigned short* vb0 = &VF[(size_t)(2 * i) * 2048 + lane * 8];
            half8 vf0[2][2], vf1[2][2];
#pragma unroll
            for (int dt = 0; dt < 2; ++dt)
#pragma unroll
                for (int j = 0; j < 2; ++j) {
                    vf0[dt][j] = *(const half8*)(vb0 + (dt * 2 + j) * 512);
                    vf1[dt][j] = *(const half8*)(vb0 + 2048 + (dt * 2 + j) * 512);
                }
            // K prefetch for next iteration
            const bool more = (i + 1 < nk);
            half8 kna[4], knb[4];
            if (more) {
                const unsigned short* kb = &KF[(size_t)(2 * i + 2) * 2048 + lane * 8];
#pragma unroll
                for (int ds = 0; ds < 4; ++ds) {
                    kna[ds] = *(const half8*)(kb + ds * 512);
                    knb[ds] = *(const half8*)(kb + 2048 + ds * 512);
                }
            }

            // S^T = K x Q for both subtiles
            floatx16 s0 = Z16, s1 = Z16;
            __builtin_amdgcn_s_setprio(1);
#pragma unroll
            for (int ds = 0; ds < 4; ++ds) s0 = MFMA32(kfa[ds], qf[ds], s0);
#pragma unroll
            for (int ds = 0; ds < 4; ++ds) s1 = MFMA32(kfb[ds], qf[ds], s1);
            __builtin_amdgcn_s_setprio(0);

            if (i == nk - 1) {  // mask needed only on the final iteration (closed form)
#pragma unroll
                for (int r = 0; r < 16; ++r) {
                    int crow = (r & 3) + ((r >> 2) << 3) + (hi32 << 2);
                    if (kt + crow > myq) s0[r] = -1e30f;
                    if (kt + 32 + crow > myq) s1[r] = -1e30f;
                }
            }

            // combined max over 64 keys: 2x-ILP tree + cross-half (VALU permlane)
            float ma[8];
#pragma unroll
            for (int r = 0; r < 8; ++r)
                ma[r] = fmaxf(fmaxf(s0[2 * r], s0[2 * r + 1]),
                              fmaxf(s1[2 * r], s1[2 * r + 1]));
            float mx = fmaxf(fmaxf(fmaxf(ma[0], ma[1]), fmaxf(ma[2], ma[3])),
                             fmaxf(fmaxf(ma[4], ma[5]), fmaxf(ma[6], ma[7])));
            mx = xhalf_max(mx);

            // defer-max: rescale only when some row's max grew past THR=8 (log2 domain)
            if (!__all(mx <= mI + 8.0f)) {
                float mn = fmaxf(mI, mx);
                float sc = exp2f(mI - mn);
                mI = mn;
                lI *= sc;
#pragma unroll
                for (int r = 0; r < 16; ++r) {
                    int src = (r & 3) + ((r >> 2) << 3) + (hi32 << 2);
                    float scb = __int_as_float(
                        __builtin_amdgcn_ds_bpermute(src << 2, __float_as_int(sc)));
                    accO0[r] *= scb;
                    accO1[r] *= scb;
                }
            }

            // P = exp2(s - m) in place; combined row-sum
#pragma unroll
            for (int r = 0; r < 16; ++r) {
                s0[r] = exp2f(s0[r] - mI);
                s1[r] = exp2f(s1[r] - mI);
            }
            float sa[8];
#pragma unroll
            for (int r = 0; r < 8; ++r)
                sa[r] = (s0[2 * r] + s0[2 * r + 1]) + (s1[2 * r] + s1[2 * r + 1]);
            float ps = ((sa[0] + sa[1]) + (sa[2] + sa[3])) +
                       ((sa[4] + sa[5]) + (sa[6] + sa[7]));
            lI += xhalf_add(ps);

            // pack subtile 0 -> A-fragments, PV
            {
                unsigned pA0 = pkrtz(s0[0], s0[1]),   pA1 = pkrtz(s0[2], s0[3]);
                unsigned pB0 = pkrtz(s0[4], s0[5]),   pB1 = pkrtz(s0[6], s0[7]);
                unsigned pC0 = pkrtz(s0[8], s0[9]),   pC1 = pkrtz(s0[10], s0[11]);
                unsigned pD0 = pkrtz(s0[12], s0[13]), pD1 = pkrtz(s0[14], s0[15]);
                unsigned w0, w1, w2, w3, u0, u1, u2, u3;
                swap32(pA0, pB0, hi32, w0, w2);
                swap32(pA1, pB1, hi32, w1, w3);
                swap32(pC0, pD0, hi32, u0, u2);
                swap32(pC1, pD1, hi32, u1, u3);
                union { unsigned u[4]; half8 h; } f0, f1;
                f0.u[0] = w0; f0.u[1] = w1; f0.u[2] = w2; f0.u[3] = w3;  // k 0..15
                f1.u[0] = u0; f1.u[1] = u1; f1.u[2] = u2; f1.u[3] = u3;  // k 16..31
                __builtin_amdgcn_s_setprio(1);
                accO0 = MFMA32(f0.h, vf0[0][0], accO0);
                accO0 = MFMA32(f1.h, vf0[0][1], accO0);
                accO1 = MFMA32(f0.h, vf0[1][0], accO1);
                accO1 = MFMA32(f1.h, vf0[1][1], accO1);
                __builtin_amdgcn_s_setprio(0);
            }
            // pack subtile 1 -> A-fragments, PV
            {
                unsigned pA0 = pkrtz(s1[0], s1[1]),   pA1 = pkrtz(s1[2], s1[3]);
                unsigned pB0 = pkrtz(s1[4], s1[5]),   pB1 = pkrtz(s1[6], s1[7]);
                unsigned pC0 = pkrtz(s1[8], s1[9]),   pC1 = pkrtz(s1[10], s1[11]);
                unsigned pD0 = pkrtz(s1[12], s1[13]), pD1 = pkrtz(s1[14], s1[15]);
                unsigned w0, w1, w2, w3, u0, u1, u2, u3;
                swap32(pA0, pB0, hi32, w0, w2);
                swap32(pA1, pB1, hi32, w1, w3);
                swap32(pC0, pD0, hi32, u0, u2);
                swap32(pC1, pD1, hi32, u1, u3);
                union { unsigned u[4]; half8 h; } f0, f1;
                f0.u[0] = w0; f0.u[1] = w1; f0.u[2] = w2; f0.u[3] = w3;  // k 32..47
                f1.u[0] = u0; f1.u[1] = u1; f1.u[2] = u2; f1.u[3] = u3;  // k 48..63
                __builtin_amdgcn_s_setprio(1);
                accO0 = MFMA32(f0.h, vf1[0][0], accO0);
                accO0 = MFMA32(f1.h, vf1[0][1], accO0);
                accO1 = MFMA32(f0.h, vf1[1][0], accO1);
                accO1 = MFMA32(f1.h, vf1[1][1], accO1);
                __builtin_amdgcn_s_setprio(0);
            }

            if (more) {
#pragma unroll
                for (int ds = 0; ds < 4; ++ds) { kfa[ds] = kna[ds]; kfb[ds] = knb[ds]; }
            }
        }

        // epilogue: O[q][d] = accO / l[q]; broadcast 1/l to C-layout rows
        const float linv = 1.0f / lI;
#pragma unroll
        for (int r = 0; r < 16; ++r) {
            int crow = (r & 3) + ((r >> 2) << 3) + (hi32 << 2);
            float lb = __int_as_float(
                __builtin_amdgcn_ds_bpermute(crow << 2, __float_as_int(linv)));
            int qrow = q0 + crow;
            size_t base = ((size_t)(b * 4096 + qrow)) * 768 + h * 64;
            Ow[base + l31] = f2h_bits(accO0[r] * lb);
            Ow[base + 32 + l31] = f2h_bits(accO1[r] * lb);
        }
    }
}

// ---------------------------------------------------------------- launch
extern "C" void kernel_launch(void* const* d_in, const int* in_sizes, int n_in,
                              void* d_out, int out_size, void* d_ws, size_t ws_size,
                              hipStream_t stream) {
    const float* x = (const float*)d_in[0];
    const float* wkqv = (const float*)d_in[1];
    const float* wproj = (const float*)d_in[2];
    const float* bproj = (const float*)d_in[3];
    float* out = (float*)d_out;

    char* ws = (char*)d_ws;
    // layout (bytes): xb 12582912 | wkqvT 3538944 | wprojB 1179648 | Q 12582912 | K 12582912 | Vt 12582912
    unsigned short* xb = (unsigned short*)(ws);
    unsigned short* wkqvT = (unsigned short*)(ws + 12582912);
    unsigned short* wprojB = (unsigned short*)(ws + 16121856);
    unsigned short* Qw = (unsigned short*)(ws + 17301504);
    unsigned short* Kw = (unsigned short*)(ws + 29884416);
    unsigned short* Vtw = (unsigned short*)(ws + 42467328);
    unsigned short* Ow = xb;  // xb dead after KQV GEMM; reuse for attention output
    if (ws_size < 55050240) return;

    conv_x_kernel<<<6144, 256, 0, stream>>>(x, xb);
    conv_wkqv_kernel<<<6912, 256, 0, stream>>>(wkqv, wkqvT);
    conv_wproj_kernel<<<576, 256, 0, stream>>>(wproj, wprojB);
    gemm_bt_kernel<0><<<64 * 18, 256, 0, stream>>>(xb, wkqvT, Qw, Kw, Vtw, nullptr, nullptr, 18);
    attn_kernel<<<768, 128, 0, stream>>>(Qw, Kw, Vtw, Ow);
    gemm_bt_kernel<1><<<64 * 6, 256, 0, stream>>>(Ow, wprojB, nullptr, nullptr, nullptr, out, bproj, 6);
}